// Round 3
// baseline (25.606 us; speedup 1.0000x reference)
//
#include <hip/hip_runtime.h>
#include <math.h>

#define SIGMA 0.2f
#define LOG2E 1.4426950408889634f

// Setup kernel (1 block, 256 threads): compute the 64x4 unit-sphere kernel
// points, pre-scaled by log2e/sigma^2, into d_ws as float4 table[l*64 + m].
__global__ __launch_bounds__(256) void corr_setup(
    const float* __restrict__ theta,
    const float* __restrict__ phi,
    float4*      __restrict__ table)
{
    const int t = threadIdx.x;          // t = m*4 + l
    const int m = t >> 2;
    const int l = t & 3;
    const float th = theta[t];
    const float ph = phi[t];
    const float st = sinf(th), ct = cosf(th);
    const float sp = sinf(ph), cp = cosf(ph);
    const float s = LOG2E / (SIGMA * SIGMA);
    table[l * 64 + m] = make_float4(st * sp * s, st * cp * s, ct * s, 0.0f);
}

// Main kernel: one wave per row, lane = kernel index m. No trig, no LDS,
// no barriers. K-table read as 4 coalesced dwordx4 loads (L2-hot, 1KB/wave).
__global__ __launch_bounds__(256) void corr_main(
    const float*  __restrict__ normal,
    const int*    __restrict__ neighbour,
    const float4* __restrict__ table,
    float*        __restrict__ out,
    int n)
{
    const int t = threadIdx.x;
    const int m = t & 63;           // lane = kernel index
    const int w = t >> 6;           // wave in block
    const int i = blockIdx.x * 4 + w;
    if (i >= n) return;

    // K-table loads (independent of everything) — issue first.
    const float4 k0 = table[  0 + m];
    const float4 k1 = table[ 64 + m];
    const float4 k2 = table[128 + m];
    const float4 k3 = table[192 + m];

    // Neighbour ids + self normal (independent) — issue together.
    const int id1 = neighbour[i * 3 + 0];
    const int id2 = neighbour[i * 3 + 1];
    const int id3 = neighbour[i * 3 + 2];

    float px[4], py[4], pz[4];
    px[0] = normal[i * 3 + 0];
    py[0] = normal[i * 3 + 1];
    pz[0] = normal[i * 3 + 2];
    px[1] = normal[id1 * 3 + 0];
    py[1] = normal[id1 * 3 + 1];
    pz[1] = normal[id1 * 3 + 2];
    px[2] = normal[id2 * 3 + 0];
    py[2] = normal[id2 * 3 + 1];
    pz[2] = normal[id2 * 3 + 2];
    px[3] = normal[id3 * 3 + 0];
    py[3] = normal[id3 * 3 + 1];
    pz[3] = normal[id3 * 3 + 2];

    const float c1 = -LOG2E / (2.0f * SIGMA * SIGMA); // multiplies (|p|^2 + 1)

    float acc0 = 0.0f, acc1 = 0.0f, acc2 = 0.0f, acc3 = 0.0f;
#pragma unroll
    for (int p = 0; p < 4; ++p) {
        const float c2 = fmaf(px[p], px[p], fmaf(py[p], py[p], fmaf(pz[p], pz[p], 1.0f))) * c1;
        acc0 += __builtin_amdgcn_exp2f(fmaf(px[p], k0.x, fmaf(py[p], k0.y, fmaf(pz[p], k0.z, c2))));
        acc1 += __builtin_amdgcn_exp2f(fmaf(px[p], k1.x, fmaf(py[p], k1.y, fmaf(pz[p], k1.z, c2))));
        acc2 += __builtin_amdgcn_exp2f(fmaf(px[p], k2.x, fmaf(py[p], k2.y, fmaf(pz[p], k2.z, c2))));
        acc3 += __builtin_amdgcn_exp2f(fmaf(px[p], k3.x, fmaf(py[p], k3.y, fmaf(pz[p], k3.z, c2))));
    }

    out[i * 64 + m] = ((acc0 + acc1) + (acc2 + acc3)) * (1.0f / 16.0f);
}

extern "C" void kernel_launch(void* const* d_in, const int* in_sizes, int n_in,
                              void* d_out, int out_size, void* d_ws, size_t ws_size,
                              hipStream_t stream) {
    const float* normal    = (const float*)d_in[0];
    const int*   neighbour = (const int*)d_in[1];
    const float* theta     = (const float*)d_in[2];
    const float* phi       = (const float*)d_in[3];
    float*       out       = (float*)d_out;
    float4*      table     = (float4*)d_ws;

    const int n = in_sizes[0] / 3;   // 50000

    hipLaunchKernelGGL(corr_setup, dim3(1), dim3(256), 0, stream,
                       theta, phi, table);

    const int blocks = (n + 3) / 4;  // 4 rows (waves) per 256-thread block
    hipLaunchKernelGGL(corr_main, dim3(blocks), dim3(256), 0, stream,
                       normal, neighbour, table, out, n);
}

// Round 4
// 19.685 us; speedup vs baseline: 1.3008x; 1.3008x over previous
//
#include <hip/hip_runtime.h>
#include <math.h>

#define SIGMA 0.2f
#define LOG2E 1.4426950408889634f

// Single fused kernel. One wave per TWO output rows; lane = kernel index m.
// No LDS, no barriers, no second launch: each lane rebuilds its own 4
// kernel points with hw trig (16 trans ops) from one coalesced float4 load;
// this overlaps with the neighbour->normal gather latency chain.
__global__ __launch_bounds__(256) void corr_fused(
    const float* __restrict__ normal,
    const int*   __restrict__ neighbour,
    const float* __restrict__ theta,
    const float* __restrict__ phi,
    float*       __restrict__ out,
    int n)
{
    const int t = threadIdx.x;
    const int m = t & 63;           // lane = kernel index
    const int w = t >> 6;           // wave in block
    const int r0 = blockIdx.x * 8 + w * 2;  // this wave's two rows
    const int r1 = r0 + 1;
    const int i0 = r0 < n ? r0 : 0; // clamp (no divergence; guard stores only)
    const int i1 = r1 < n ? r1 : 0;

    // ---- issue all row-dependent loads first (independent of trig) ----
    const int a1 = neighbour[i0 * 3 + 0];
    const int a2 = neighbour[i0 * 3 + 1];
    const int a3 = neighbour[i0 * 3 + 2];
    const int b1 = neighbour[i1 * 3 + 0];
    const int b2 = neighbour[i1 * 3 + 1];
    const int b3 = neighbour[i1 * 3 + 2];

    float ax[4], ay[4], az[4], bx[4], by[4], bz[4];
    ax[0] = normal[i0 * 3 + 0]; ay[0] = normal[i0 * 3 + 1]; az[0] = normal[i0 * 3 + 2];
    bx[0] = normal[i1 * 3 + 0]; by[0] = normal[i1 * 3 + 1]; bz[0] = normal[i1 * 3 + 2];
    ax[1] = normal[a1 * 3 + 0]; ay[1] = normal[a1 * 3 + 1]; az[1] = normal[a1 * 3 + 2];
    ax[2] = normal[a2 * 3 + 0]; ay[2] = normal[a2 * 3 + 1]; az[2] = normal[a2 * 3 + 2];
    ax[3] = normal[a3 * 3 + 0]; ay[3] = normal[a3 * 3 + 1]; az[3] = normal[a3 * 3 + 2];
    bx[1] = normal[b1 * 3 + 0]; by[1] = normal[b1 * 3 + 1]; bz[1] = normal[b1 * 3 + 2];
    bx[2] = normal[b2 * 3 + 0]; by[2] = normal[b2 * 3 + 1]; bz[2] = normal[b2 * 3 + 2];
    bx[3] = normal[b3 * 3 + 0]; by[3] = normal[b3 * 3 + 1]; bz[3] = normal[b3 * 3 + 2];

    // ---- per-lane kernel points (hw trig; overlaps gather latency) ----
    const float4 th = *(const float4*)(theta + 4 * m);
    const float4 ph = *(const float4*)(phi + 4 * m);
    const float s = LOG2E / (SIGMA * SIGMA);
    float kxs[4], kys[4], kzs[4];
    {
        const float st0 = __sinf(th.x), st1 = __sinf(th.y), st2 = __sinf(th.z), st3 = __sinf(th.w);
        const float ct0 = __cosf(th.x), ct1 = __cosf(th.y), ct2 = __cosf(th.z), ct3 = __cosf(th.w);
        const float sp0 = __sinf(ph.x), sp1 = __sinf(ph.y), sp2 = __sinf(ph.z), sp3 = __sinf(ph.w);
        const float cp0 = __cosf(ph.x), cp1 = __cosf(ph.y), cp2 = __cosf(ph.z), cp3 = __cosf(ph.w);
        kxs[0] = st0 * sp0 * s; kys[0] = st0 * cp0 * s; kzs[0] = ct0 * s;
        kxs[1] = st1 * sp1 * s; kys[1] = st1 * cp1 * s; kzs[1] = ct1 * s;
        kxs[2] = st2 * sp2 * s; kys[2] = st2 * cp2 * s; kzs[2] = ct2 * s;
        kxs[3] = st3 * sp3 * s; kys[3] = st3 * cp3 * s; kzs[3] = ct3 * s;
    }

    const float c1 = -LOG2E / (2.0f * SIGMA * SIGMA); // multiplies (|p|^2 + 1)

    float accA0 = 0.0f, accA1 = 0.0f, accB0 = 0.0f, accB1 = 0.0f;
#pragma unroll
    for (int p = 0; p < 4; ++p) {
        const float cA = fmaf(ax[p], ax[p], fmaf(ay[p], ay[p], fmaf(az[p], az[p], 1.0f))) * c1;
        const float cB = fmaf(bx[p], bx[p], fmaf(by[p], by[p], fmaf(bz[p], bz[p], 1.0f))) * c1;
#pragma unroll
        for (int l = 0; l < 4; ++l) {
            const float gA = fmaf(ax[p], kxs[l], fmaf(ay[p], kys[l], fmaf(az[p], kzs[l], cA)));
            const float gB = fmaf(bx[p], kxs[l], fmaf(by[p], kys[l], fmaf(bz[p], kzs[l], cB)));
            if (l & 1) { accA1 += __builtin_amdgcn_exp2f(gA); accB1 += __builtin_amdgcn_exp2f(gB); }
            else       { accA0 += __builtin_amdgcn_exp2f(gA); accB0 += __builtin_amdgcn_exp2f(gB); }
        }
    }

    if (r0 < n) out[r0 * 64 + m] = (accA0 + accA1) * (1.0f / 16.0f);
    if (r1 < n) out[r1 * 64 + m] = (accB0 + accB1) * (1.0f / 16.0f);
}

extern "C" void kernel_launch(void* const* d_in, const int* in_sizes, int n_in,
                              void* d_out, int out_size, void* d_ws, size_t ws_size,
                              hipStream_t stream) {
    const float* normal    = (const float*)d_in[0];
    const int*   neighbour = (const int*)d_in[1];
    const float* theta     = (const float*)d_in[2];
    const float* phi       = (const float*)d_in[3];
    float*       out       = (float*)d_out;

    const int n = in_sizes[0] / 3;   // 50000
    const int blocks = (n + 7) / 8;  // 8 rows per 256-thread block

    hipLaunchKernelGGL(corr_fused, dim3(blocks), dim3(256), 0, stream,
                       normal, neighbour, theta, phi, out, n);
}

// Round 5
// 18.603 us; speedup vs baseline: 1.3764x; 1.0582x over previous
//
#include <hip/hip_runtime.h>
#include <math.h>

#define SIGMA 0.2f
#define LOG2E 1.4426950408889634f

typedef float f32x2 __attribute__((ext_vector_type(2)));

// Single fused kernel. One wave per TWO output rows; lane = kernel index m.
// Rows A,B packed into float2 lanes -> inner loop runs on v_pk_fma_f32
// (packed fp32, 2 FMAs/issue), ~40% fewer VALU issues than scalar.
__global__ __launch_bounds__(256) void corr_fused(
    const float* __restrict__ normal,
    const int*   __restrict__ neighbour,
    const float* __restrict__ theta,
    const float* __restrict__ phi,
    float*       __restrict__ out,
    int n)
{
    const int t = threadIdx.x;
    const int m = t & 63;           // lane = kernel index
    const int w = t >> 6;           // wave in block
    const int r0 = blockIdx.x * 8 + w * 2;  // this wave's two rows
    const int r1 = r0 + 1;
    const int i0 = r0 < n ? r0 : 0; // clamp (guard stores only)
    const int i1 = r1 < n ? r1 : 0;

    // ---- issue all row-dependent loads first (independent of trig) ----
    const int a1 = neighbour[i0 * 3 + 0];
    const int a2 = neighbour[i0 * 3 + 1];
    const int a3 = neighbour[i0 * 3 + 2];
    const int b1 = neighbour[i1 * 3 + 0];
    const int b2 = neighbour[i1 * 3 + 1];
    const int b3 = neighbour[i1 * 3 + 2];

    f32x2 px[4], py[4], pz[4];      // .x = row A point, .y = row B point
    px[0] = (f32x2){normal[i0 * 3 + 0], normal[i1 * 3 + 0]};
    py[0] = (f32x2){normal[i0 * 3 + 1], normal[i1 * 3 + 1]};
    pz[0] = (f32x2){normal[i0 * 3 + 2], normal[i1 * 3 + 2]};
    px[1] = (f32x2){normal[a1 * 3 + 0], normal[b1 * 3 + 0]};
    py[1] = (f32x2){normal[a1 * 3 + 1], normal[b1 * 3 + 1]};
    pz[1] = (f32x2){normal[a1 * 3 + 2], normal[b1 * 3 + 2]};
    px[2] = (f32x2){normal[a2 * 3 + 0], normal[b2 * 3 + 0]};
    py[2] = (f32x2){normal[a2 * 3 + 1], normal[b2 * 3 + 1]};
    pz[2] = (f32x2){normal[a2 * 3 + 2], normal[b2 * 3 + 2]};
    px[3] = (f32x2){normal[a3 * 3 + 0], normal[b3 * 3 + 0]};
    py[3] = (f32x2){normal[a3 * 3 + 1], normal[b3 * 3 + 1]};
    pz[3] = (f32x2){normal[a3 * 3 + 2], normal[b3 * 3 + 2]};

    // ---- per-lane kernel points (hw trig; overlaps gather latency) ----
    const float4 th = *(const float4*)(theta + 4 * m);
    const float4 ph = *(const float4*)(phi + 4 * m);
    const float s = LOG2E / (SIGMA * SIGMA);
    float kxs[4], kys[4], kzs[4];
    {
        const float st0 = __sinf(th.x), st1 = __sinf(th.y), st2 = __sinf(th.z), st3 = __sinf(th.w);
        const float ct0 = __cosf(th.x), ct1 = __cosf(th.y), ct2 = __cosf(th.z), ct3 = __cosf(th.w);
        const float sp0 = __sinf(ph.x), sp1 = __sinf(ph.y), sp2 = __sinf(ph.z), sp3 = __sinf(ph.w);
        const float cp0 = __cosf(ph.x), cp1 = __cosf(ph.y), cp2 = __cosf(ph.z), cp3 = __cosf(ph.w);
        kxs[0] = st0 * sp0 * s; kys[0] = st0 * cp0 * s; kzs[0] = ct0 * s;
        kxs[1] = st1 * sp1 * s; kys[1] = st1 * cp1 * s; kzs[1] = ct1 * s;
        kxs[2] = st2 * sp2 * s; kys[2] = st2 * cp2 * s; kzs[2] = ct2 * s;
        kxs[3] = st3 * sp3 * s; kys[3] = st3 * cp3 * s; kzs[3] = ct3 * s;
    }

    const float c1 = -LOG2E / (2.0f * SIGMA * SIGMA); // multiplies (|p|^2 + 1)
    const f32x2 onev = (f32x2){1.0f, 1.0f};

    f32x2 acc0 = (f32x2){0.0f, 0.0f};
    f32x2 acc1 = (f32x2){0.0f, 0.0f};
#pragma unroll
    for (int p = 0; p < 4; ++p) {
        // c2 = (|p|^2 + 1) * c1, packed over rows A,B (contracts to v_pk_fma)
        const f32x2 c2 = (px[p] * px[p] + (py[p] * py[p] + (pz[p] * pz[p] + onev))) * c1;
#pragma unroll
        for (int l = 0; l < 4; ++l) {
            // g = px*kx + py*ky + pz*kz + c2, packed (3x v_pk_fma_f32)
            const f32x2 g = px[p] * kxs[l] + (py[p] * kys[l] + (pz[p] * kzs[l] + c2));
            const f32x2 e = (f32x2){__builtin_amdgcn_exp2f(g.x), __builtin_amdgcn_exp2f(g.y)};
            if (l & 1) acc1 += e; else acc0 += e;
        }
    }

    const f32x2 res = (acc0 + acc1) * (1.0f / 16.0f);
    if (r0 < n) out[r0 * 64 + m] = res.x;
    if (r1 < n) out[r1 * 64 + m] = res.y;
}

extern "C" void kernel_launch(void* const* d_in, const int* in_sizes, int n_in,
                              void* d_out, int out_size, void* d_ws, size_t ws_size,
                              hipStream_t stream) {
    const float* normal    = (const float*)d_in[0];
    const int*   neighbour = (const int*)d_in[1];
    const float* theta     = (const float*)d_in[2];
    const float* phi       = (const float*)d_in[3];
    float*       out       = (float*)d_out;

    const int n = in_sizes[0] / 3;   // 50000
    const int blocks = (n + 7) / 8;  // 8 rows per 256-thread block

    hipLaunchKernelGGL(corr_fused, dim3(blocks), dim3(256), 0, stream,
                       normal, neighbour, theta, phi, out, n);
}

// Round 6
// 18.543 us; speedup vs baseline: 1.3809x; 1.0033x over previous
//
#include <hip/hip_runtime.h>
#include <math.h>

#define SIGMA 0.2f
#define LOG2E 1.4426950408889634f

typedef float f32x2 __attribute__((ext_vector_type(2)));

// One wave per FOUR output rows (two packed f32x2 pairs); lane = kernel
// index m. Packed rows run on v_pk_fma_f32; the 16 hw-trig ops + k-loads
// amortize over 4 rows; two independent packed chains give ILP to hide
// exp/trans latency. 16 rows per 256-thread block -> 3125 blocks (exact).
__global__ __launch_bounds__(256) void corr_fused(
    const float* __restrict__ normal,
    const int*   __restrict__ neighbour,
    const float* __restrict__ theta,
    const float* __restrict__ phi,
    float*       __restrict__ out,
    int n)
{
    const int t = threadIdx.x;
    const int m = t & 63;           // lane = kernel index
    const int w = t >> 6;           // wave in block
    const int base = blockIdx.x * 16 + w * 4;
    if (base >= n) return;
    const int r0 = base, r1 = base + 1, r2 = base + 2, r3 = base + 3;
    const int i0 = r0, i1 = r1 < n ? r1 : r0, i2 = r2 < n ? r2 : r0, i3 = r3 < n ? r3 : r0;

    // ---- issue all neighbour loads (independent) ----
    const int a1 = neighbour[i0 * 3 + 0], a2 = neighbour[i0 * 3 + 1], a3 = neighbour[i0 * 3 + 2];
    const int b1 = neighbour[i1 * 3 + 0], b2 = neighbour[i1 * 3 + 1], b3 = neighbour[i1 * 3 + 2];
    const int c1i = neighbour[i2 * 3 + 0], c2i = neighbour[i2 * 3 + 1], c3i = neighbour[i2 * 3 + 2];
    const int d1 = neighbour[i3 * 3 + 0], d2 = neighbour[i3 * 3 + 1], d3 = neighbour[i3 * 3 + 2];

    // ---- gather normals: pair A = rows (r0,r1), pair B = rows (r2,r3) ----
    f32x2 Ax[4], Ay[4], Az[4], Bx[4], By[4], Bz[4];
    Ax[0] = (f32x2){normal[i0 * 3 + 0], normal[i1 * 3 + 0]};
    Ay[0] = (f32x2){normal[i0 * 3 + 1], normal[i1 * 3 + 1]};
    Az[0] = (f32x2){normal[i0 * 3 + 2], normal[i1 * 3 + 2]};
    Ax[1] = (f32x2){normal[a1 * 3 + 0], normal[b1 * 3 + 0]};
    Ay[1] = (f32x2){normal[a1 * 3 + 1], normal[b1 * 3 + 1]};
    Az[1] = (f32x2){normal[a1 * 3 + 2], normal[b1 * 3 + 2]};
    Ax[2] = (f32x2){normal[a2 * 3 + 0], normal[b2 * 3 + 0]};
    Ay[2] = (f32x2){normal[a2 * 3 + 1], normal[b2 * 3 + 1]};
    Az[2] = (f32x2){normal[a2 * 3 + 2], normal[b2 * 3 + 2]};
    Ax[3] = (f32x2){normal[a3 * 3 + 0], normal[b3 * 3 + 0]};
    Ay[3] = (f32x2){normal[a3 * 3 + 1], normal[b3 * 3 + 1]};
    Az[3] = (f32x2){normal[a3 * 3 + 2], normal[b3 * 3 + 2]};
    Bx[0] = (f32x2){normal[i2 * 3 + 0], normal[i3 * 3 + 0]};
    By[0] = (f32x2){normal[i2 * 3 + 1], normal[i3 * 3 + 1]};
    Bz[0] = (f32x2){normal[i2 * 3 + 2], normal[i3 * 3 + 2]};
    Bx[1] = (f32x2){normal[c1i * 3 + 0], normal[d1 * 3 + 0]};
    By[1] = (f32x2){normal[c1i * 3 + 1], normal[d1 * 3 + 1]};
    Bz[1] = (f32x2){normal[c1i * 3 + 2], normal[d1 * 3 + 2]};
    Bx[2] = (f32x2){normal[c2i * 3 + 0], normal[d2 * 3 + 0]};
    By[2] = (f32x2){normal[c2i * 3 + 1], normal[d2 * 3 + 1]};
    Bz[2] = (f32x2){normal[c2i * 3 + 2], normal[d2 * 3 + 2]};
    Bx[3] = (f32x2){normal[c3i * 3 + 0], normal[d3 * 3 + 0]};
    By[3] = (f32x2){normal[c3i * 3 + 1], normal[d3 * 3 + 1]};
    Bz[3] = (f32x2){normal[c3i * 3 + 2], normal[d3 * 3 + 2]};

    // ---- per-lane kernel points (hw trig; overlaps gather latency) ----
    const float4 th = *(const float4*)(theta + 4 * m);
    const float4 ph = *(const float4*)(phi + 4 * m);
    const float s = LOG2E / (SIGMA * SIGMA);
    float kxs[4], kys[4], kzs[4];
    {
        const float st0 = __sinf(th.x), st1 = __sinf(th.y), st2 = __sinf(th.z), st3 = __sinf(th.w);
        const float ct0 = __cosf(th.x), ct1 = __cosf(th.y), ct2 = __cosf(th.z), ct3 = __cosf(th.w);
        const float sp0 = __sinf(ph.x), sp1 = __sinf(ph.y), sp2 = __sinf(ph.z), sp3 = __sinf(ph.w);
        const float cp0 = __cosf(ph.x), cp1 = __cosf(ph.y), cp2 = __cosf(ph.z), cp3 = __cosf(ph.w);
        kxs[0] = st0 * sp0 * s; kys[0] = st0 * cp0 * s; kzs[0] = ct0 * s;
        kxs[1] = st1 * sp1 * s; kys[1] = st1 * cp1 * s; kzs[1] = ct1 * s;
        kxs[2] = st2 * sp2 * s; kys[2] = st2 * cp2 * s; kzs[2] = ct2 * s;
        kxs[3] = st3 * sp3 * s; kys[3] = st3 * cp3 * s; kzs[3] = ct3 * s;
    }

    const float cc = -LOG2E / (2.0f * SIGMA * SIGMA); // multiplies (|p|^2 + 1)
    const f32x2 onev = (f32x2){1.0f, 1.0f};

    f32x2 accA0 = (f32x2){0.0f, 0.0f}, accA1 = (f32x2){0.0f, 0.0f};
    f32x2 accB0 = (f32x2){0.0f, 0.0f}, accB1 = (f32x2){0.0f, 0.0f};
#pragma unroll
    for (int p = 0; p < 4; ++p) {
        const f32x2 cA = (Ax[p] * Ax[p] + (Ay[p] * Ay[p] + (Az[p] * Az[p] + onev))) * cc;
        const f32x2 cB = (Bx[p] * Bx[p] + (By[p] * By[p] + (Bz[p] * Bz[p] + onev))) * cc;
#pragma unroll
        for (int l = 0; l < 4; ++l) {
            const f32x2 gA = Ax[p] * kxs[l] + (Ay[p] * kys[l] + (Az[p] * kzs[l] + cA));
            const f32x2 gB = Bx[p] * kxs[l] + (By[p] * kys[l] + (Bz[p] * kzs[l] + cB));
            const f32x2 eA = (f32x2){__builtin_amdgcn_exp2f(gA.x), __builtin_amdgcn_exp2f(gA.y)};
            const f32x2 eB = (f32x2){__builtin_amdgcn_exp2f(gB.x), __builtin_amdgcn_exp2f(gB.y)};
            if (l & 1) { accA1 += eA; accB1 += eB; }
            else       { accA0 += eA; accB0 += eB; }
        }
    }

    const f32x2 resA = (accA0 + accA1) * (1.0f / 16.0f);
    const f32x2 resB = (accB0 + accB1) * (1.0f / 16.0f);
    out[r0 * 64 + m] = resA.x;
    if (r1 < n) out[r1 * 64 + m] = resA.y;
    if (r2 < n) out[r2 * 64 + m] = resB.x;
    if (r3 < n) out[r3 * 64 + m] = resB.y;
}

extern "C" void kernel_launch(void* const* d_in, const int* in_sizes, int n_in,
                              void* d_out, int out_size, void* d_ws, size_t ws_size,
                              hipStream_t stream) {
    const float* normal    = (const float*)d_in[0];
    const int*   neighbour = (const int*)d_in[1];
    const float* theta     = (const float*)d_in[2];
    const float* phi       = (const float*)d_in[3];
    float*       out       = (float*)d_out;

    const int n = in_sizes[0] / 3;    // 50000
    const int blocks = (n + 15) / 16; // 16 rows per 256-thread block (exact for 50000)

    hipLaunchKernelGGL(corr_fused, dim3(blocks), dim3(256), 0, stream,
                       normal, neighbour, theta, phi, out, n);
}